// Round 11
// baseline (147.786 us; speedup 1.0000x reference)
//
#include <hip/hip_runtime.h>
#include <math.h>

#define BATCH  512
#define NROWS  256
#define NVECS  8
#define VSIZE  128
#define DIM    1024   // NVECS*VSIZE
#define NCOMBO 256

// ---------------------------------------------------------------------------
// R11 = R10 with the compile fix: __builtin_nontemporal_store requires a
// NATIVE clang vector type, not HIP_vector_type<float,4>. Store through
// float ext_vector_type(4) instead (same global_store_dwordx4 + nt bit).
//
// Experiment (unchanged from R10): R7 base (verified best, 140.6us) + nt
// output stores so the 128 MiB write-only stream bypasses L2 allocation
// instead of evicting the L2-resident W (1 MB) / Q (2 MB) inputs.
//
// Ledger: R1 schedule null / R2 occupancy null / R4+R8 work-removal null /
// R5+R6 split regress / R7 DPP -4.3 / R9 prologue null. Last orthogonal
// lever; null here => R7 structure is the floor.
// ---------------------------------------------------------------------------

typedef float nfloat4 __attribute__((ext_vector_type(4)));

// sum over each 8-lane group, result in all 8 lanes (pure VALU, R7-verified)
__device__ __forceinline__ float dpp8_sum(float x) {
  int v;
  v = __builtin_amdgcn_update_dpp(0, __float_as_int(x), 0xB1, 0xF, 0xF, true);
  x += __int_as_float(v);                       // + lane^1  (quad_perm 1,0,3,2)
  v = __builtin_amdgcn_update_dpp(0, __float_as_int(x), 0x4E, 0xF, 0xF, true);
  x += __int_as_float(v);                       // + lane^2  (quad_perm 2,3,0,1)
  v = __builtin_amdgcn_update_dpp(0, __float_as_int(x), 0x141, 0xF, 0xF, true);
  x += __int_as_float(v);                       // + other quad (row_half_mirror)
  return x;
}

__global__ __launch_bounds__(256) void fused_kernel(
    const float* __restrict__ q, const float* __restrict__ w,
    float* __restrict__ out) {
  __shared__ __align__(16) float Ws[8 * 1056];  // 33 KB: 8 rows, 8x(128+4)
  const int t    = threadIdx.x;
  const int wv   = t >> 6, lane = t & 63;
  const int bs   = blockIdx.x * 8, rs = blockIdx.y * 8;
  const int n    = lane >> 3, c = lane & 7;
  const int koff = n * VSIZE + c * 16;
  const int b0   = bs + 2 * wv;

  // stage W tile (8 x 1024 floats): consecutive threads -> consecutive 16B
  #pragma unroll
  for (int i = 0; i < 8; ++i) {
    int f = i * 256 + t;        // float4 index 0..2047
    int g = f << 2;             // element index
    int row = g >> 10, e = g & 1023;
    float4 v = *(const float4*)(w + (size_t)(rs + row) * DIM + e);
    *(float4*)(Ws + row * 1056 + (e >> 7) * 132 + (e & 127)) = v;
  }

  // Q rows -> registers; inline sub-vector inverse norms via DPP reduce.
  float4 qa[4], qb[4];
  float qs0 = 0.f, qs1 = 0.f;
  {
    const float* Q0 = q + (size_t)b0 * DIM + koff;
    #pragma unroll
    for (int j = 0; j < 4; ++j) {
      qa[j] = *(const float4*)(Q0 + 4 * j);
      qb[j] = *(const float4*)(Q0 + DIM + 4 * j);
      qs0 = fmaf(qa[j].x, qa[j].x, qs0); qs0 = fmaf(qa[j].y, qa[j].y, qs0);
      qs0 = fmaf(qa[j].z, qa[j].z, qs0); qs0 = fmaf(qa[j].w, qa[j].w, qs0);
      qs1 = fmaf(qb[j].x, qb[j].x, qs1); qs1 = fmaf(qb[j].y, qb[j].y, qs1);
      qs1 = fmaf(qb[j].z, qb[j].z, qs1); qs1 = fmaf(qb[j].w, qb[j].w, qs1);
    }
  }
  qs0 = dpp8_sum(qs0);
  qs1 = dpp8_sum(qs1);
  const float iq0 = 1.0f / fmaxf(sqrtf(qs0), 1e-8f);
  const float iq1 = 1.0f / fmaxf(sqrtf(qs1), 1e-8f);

  __syncthreads();

  const float* Wb = Ws + n * 132 + c * 16;
  float* out0 = out + ((size_t)b0 * NROWS + rs) * NCOMBO + lane * 4;

  #pragma unroll 2
  for (int r = 0; r < 8; ++r) {
    // --- dots + w-norm for row rs+r (W from LDS) ---
    const float* Wr = Wb + r * 1056;
    float s0 = 0.f, s1 = 0.f, wss = 0.f;
    #pragma unroll
    for (int j = 0; j < 4; ++j) {
      float4 w4 = *(const float4*)(Wr + 4 * j);
      s0 = fmaf(qa[j].x, w4.x, s0); s0 = fmaf(qa[j].y, w4.y, s0);
      s0 = fmaf(qa[j].z, w4.z, s0); s0 = fmaf(qa[j].w, w4.w, s0);
      s1 = fmaf(qb[j].x, w4.x, s1); s1 = fmaf(qb[j].y, w4.y, s1);
      s1 = fmaf(qb[j].z, w4.z, s1); s1 = fmaf(qb[j].w, w4.w, s1);
      wss = fmaf(w4.x, w4.x, wss); wss = fmaf(w4.y, w4.y, wss);
      wss = fmaf(w4.z, w4.z, wss); wss = fmaf(w4.w, w4.w, wss);
    }
    s0  = dpp8_sum(s0);
    s1  = dpp8_sum(s1);
    wss = dpp8_sum(wss);
    const float iw  = 1.0f / fmaxf(sqrtf(wss), 1e-8f);
    const float cs0 = fmaxf(s0 * iq0 * iw, 0.f);
    const float cs1 = fmaxf(s1 * iq1 * iw, 0.f);

    // broadcast cs[n] from lane 8n to all lanes (uniform index -> readlane)
    float v0[8], v1[8];
    #pragma unroll
    for (int j = 0; j < 8; ++j) {
      v0[j] = __shfl(cs0, j * 8, 64);
      v1[j] = __shfl(cs1, j * 8, 64);
    }

    // --- expand + nt-store both b-rows for this r ---
    #pragma unroll
    for (int pp = 0; pp < 2; ++pp) {
      const float* v = pp ? v1 : v0;
      float t2 = (lane & 1)  ? 1.f - v[2] : v[2];
      float t3 = (lane & 2)  ? 1.f - v[3] : v[3];
      float t4 = (lane & 4)  ? 1.f - v[4] : v[4];
      float t5 = (lane & 8)  ? 1.f - v[5] : v[5];
      float t6 = (lane & 16) ? 1.f - v[6] : v[6];
      float t7 = (lane & 32) ? 1.f - v[7] : v[7];
      float base = ((t2 * t3) * (t4 * t5)) * (t6 * t7);
      float c0 = v[0], c1 = v[1];
      nfloat4 o;
      o.x = base * (c0 * c1);
      o.y = base * ((1.f - c0) * c1);
      o.z = base * (c0 * (1.f - c1));
      o.w = base * ((1.f - c0) * (1.f - c1));
      __builtin_nontemporal_store(
          o, (nfloat4*)(out0 + ((size_t)pp * NROWS + r) * NCOMBO));
    }
  }
}

// ---------------------------------------------------------------------------
extern "C" void kernel_launch(void* const* d_in, const int* in_sizes, int n_in,
                              void* d_out, int out_size, void* d_ws, size_t ws_size,
                              hipStream_t stream) {
  const float* query  = (const float*)d_in[0];   // [512][1024]
  const float* weight = (const float*)d_in[1];   // [256][1024]
  float* out = (float*)d_out;                    // [512][256][256]
  (void)d_ws; (void)ws_size;

  hipLaunchKernelGGL(fused_kernel, dim3(64, 32), dim3(256), 0, stream,
                     query, weight, out);
}

// Round 12
// 140.423 us; speedup vs baseline: 1.0524x; 1.0524x over previous
//
#include <hip/hip_runtime.h>
#include <math.h>

#define BATCH  512
#define NROWS  256
#define NVECS  8
#define VSIZE  128
#define DIM    1024   // NVECS*VSIZE
#define NCOMBO 256

// ---------------------------------------------------------------------------
// FINAL (R12) = R7, the session's verified best (140.6us; baseline 144.9).
//
// Structure: single fused kernel, 8b x 8r tile, 256 thr (4 waves), grid
// 64x32. Coalesced W->LDS staging (padded 132-float segments), Q rows in
// VGPRs, all 8-lane-group reductions as DPP v_add_f32 (quad_perm xor1/xor2
// + row_half_mirror) -- pure VALU, no DS-pipe swizzles (the R7 win, -4.3us).
// readlane broadcasts; expand + store-streaming r-loop.
//
// Session ledger (why this is the floor):
//   R1  store-schedule decouple      null    (chain not binding)
//   R2  2x occupancy (18KB LDS)      null    (DS pipe is per-CU)
//   R4  w-norm hoist (-17% insts)    null    (r-loop overlap-absorbed)
//   R5  split, divergent W reads     +15us   (documented trap, confirmed)
//   R6  split, LDS-staged A          +9us    (fusion overlap load-bearing)
//   R7  DPP instead of ds_swizzle    -4.3us  WIN
//   R8  conflict-free LDS + hoists   +1.4us  (moved conflicts to writes)
//   R9  16b tile, 512 thr            +1.5us  (prologue not binding)
//   R11 nontemporal stores           +7.2us  (L2 write-combining helps)
// Region ~59us vs 20.5us pure-store floor at the measured 6.6 TB/s fill
// ceiling; every orthogonal lever measured null or negative.
// ---------------------------------------------------------------------------

// sum over each 8-lane group, result in all 8 lanes (pure VALU)
__device__ __forceinline__ float dpp8_sum(float x) {
  int v;
  v = __builtin_amdgcn_update_dpp(0, __float_as_int(x), 0xB1, 0xF, 0xF, true);
  x += __int_as_float(v);                       // + lane^1  (quad_perm 1,0,3,2)
  v = __builtin_amdgcn_update_dpp(0, __float_as_int(x), 0x4E, 0xF, 0xF, true);
  x += __int_as_float(v);                       // + lane^2  (quad_perm 2,3,0,1)
  v = __builtin_amdgcn_update_dpp(0, __float_as_int(x), 0x141, 0xF, 0xF, true);
  x += __int_as_float(v);                       // + other quad (row_half_mirror)
  return x;
}

__global__ __launch_bounds__(256) void fused_kernel(
    const float* __restrict__ q, const float* __restrict__ w,
    float* __restrict__ out) {
  __shared__ __align__(16) float Ws[8 * 1056];  // 33 KB: 8 rows, 8x(128+4)
  const int t    = threadIdx.x;
  const int wv   = t >> 6, lane = t & 63;
  const int bs   = blockIdx.x * 8, rs = blockIdx.y * 8;
  const int n    = lane >> 3, c = lane & 7;
  const int koff = n * VSIZE + c * 16;
  const int b0   = bs + 2 * wv;

  // stage W tile (8 x 1024 floats): consecutive threads -> consecutive 16B
  #pragma unroll
  for (int i = 0; i < 8; ++i) {
    int f = i * 256 + t;        // float4 index 0..2047
    int g = f << 2;             // element index
    int row = g >> 10, e = g & 1023;
    float4 v = *(const float4*)(w + (size_t)(rs + row) * DIM + e);
    *(float4*)(Ws + row * 1056 + (e >> 7) * 132 + (e & 127)) = v;
  }

  // Q rows -> registers; inline sub-vector inverse norms via DPP reduce.
  float4 qa[4], qb[4];
  float qs0 = 0.f, qs1 = 0.f;
  {
    const float* Q0 = q + (size_t)b0 * DIM + koff;
    #pragma unroll
    for (int j = 0; j < 4; ++j) {
      qa[j] = *(const float4*)(Q0 + 4 * j);
      qb[j] = *(const float4*)(Q0 + DIM + 4 * j);
      qs0 = fmaf(qa[j].x, qa[j].x, qs0); qs0 = fmaf(qa[j].y, qa[j].y, qs0);
      qs0 = fmaf(qa[j].z, qa[j].z, qs0); qs0 = fmaf(qa[j].w, qa[j].w, qs0);
      qs1 = fmaf(qb[j].x, qb[j].x, qs1); qs1 = fmaf(qb[j].y, qb[j].y, qs1);
      qs1 = fmaf(qb[j].z, qb[j].z, qs1); qs1 = fmaf(qb[j].w, qb[j].w, qs1);
    }
  }
  qs0 = dpp8_sum(qs0);
  qs1 = dpp8_sum(qs1);
  const float iq0 = 1.0f / fmaxf(sqrtf(qs0), 1e-8f);
  const float iq1 = 1.0f / fmaxf(sqrtf(qs1), 1e-8f);

  __syncthreads();

  const float* Wb = Ws + n * 132 + c * 16;
  float* out0 = out + ((size_t)b0 * NROWS + rs) * NCOMBO + lane * 4;

  #pragma unroll 2
  for (int r = 0; r < 8; ++r) {
    // --- dots + w-norm for row rs+r (W from LDS) ---
    const float* Wr = Wb + r * 1056;
    float s0 = 0.f, s1 = 0.f, wss = 0.f;
    #pragma unroll
    for (int j = 0; j < 4; ++j) {
      float4 w4 = *(const float4*)(Wr + 4 * j);
      s0 = fmaf(qa[j].x, w4.x, s0); s0 = fmaf(qa[j].y, w4.y, s0);
      s0 = fmaf(qa[j].z, w4.z, s0); s0 = fmaf(qa[j].w, w4.w, s0);
      s1 = fmaf(qb[j].x, w4.x, s1); s1 = fmaf(qb[j].y, w4.y, s1);
      s1 = fmaf(qb[j].z, w4.z, s1); s1 = fmaf(qb[j].w, w4.w, s1);
      wss = fmaf(w4.x, w4.x, wss); wss = fmaf(w4.y, w4.y, wss);
      wss = fmaf(w4.z, w4.z, wss); wss = fmaf(w4.w, w4.w, wss);
    }
    s0  = dpp8_sum(s0);
    s1  = dpp8_sum(s1);
    wss = dpp8_sum(wss);
    const float iw  = 1.0f / fmaxf(sqrtf(wss), 1e-8f);
    const float cs0 = fmaxf(s0 * iq0 * iw, 0.f);
    const float cs1 = fmaxf(s1 * iq1 * iw, 0.f);

    // broadcast cs[n] from lane 8n to all lanes (uniform index -> readlane)
    float v0[8], v1[8];
    #pragma unroll
    for (int j = 0; j < 8; ++j) {
      v0[j] = __shfl(cs0, j * 8, 64);
      v1[j] = __shfl(cs1, j * 8, 64);
    }

    // --- expand + store both b-rows for this r (stores spread over loop) ---
    #pragma unroll
    for (int pp = 0; pp < 2; ++pp) {
      const float* v = pp ? v1 : v0;
      float t2 = (lane & 1)  ? 1.f - v[2] : v[2];
      float t3 = (lane & 2)  ? 1.f - v[3] : v[3];
      float t4 = (lane & 4)  ? 1.f - v[4] : v[4];
      float t5 = (lane & 8)  ? 1.f - v[5] : v[5];
      float t6 = (lane & 16) ? 1.f - v[6] : v[6];
      float t7 = (lane & 32) ? 1.f - v[7] : v[7];
      float base = ((t2 * t3) * (t4 * t5)) * (t6 * t7);
      float c0 = v[0], c1 = v[1];
      float4 o;
      o.x = base * (c0 * c1);
      o.y = base * ((1.f - c0) * c1);
      o.z = base * (c0 * (1.f - c1));
      o.w = base * ((1.f - c0) * (1.f - c1));
      *(float4*)(out0 + ((size_t)pp * NROWS + r) * NCOMBO) = o;
    }
  }
}

// ---------------------------------------------------------------------------
extern "C" void kernel_launch(void* const* d_in, const int* in_sizes, int n_in,
                              void* d_out, int out_size, void* d_ws, size_t ws_size,
                              hipStream_t stream) {
  const float* query  = (const float*)d_in[0];   // [512][1024]
  const float* weight = (const float*)d_in[1];   // [256][1024]
  float* out = (float*)d_out;                    // [512][256][256]
  (void)d_ws; (void)ws_size;

  hipLaunchKernelGGL(fused_kernel, dim3(64, 32), dim3(256), 0, stream,
                     query, weight, out);
}